// Round 8
// baseline (254.080 us; speedup 1.0000x reference)
//
#include <hip/hip_runtime.h>
#include <hip/hip_bf16.h>
#include <math.h>

typedef __hip_bfloat16 bf16;
typedef __attribute__((ext_vector_type(8))) short short8;
typedef __attribute__((ext_vector_type(4))) short short4v;
typedef __attribute__((ext_vector_type(4))) float floatx4;

#define MFMA16(a, b, c) __builtin_amdgcn_mfma_f32_16x16x32_bf16((a), (b), (c), 0, 0, 0)

typedef const __attribute__((address_space(1))) void* as1_cvp;
typedef __attribute__((address_space(3))) void* as3_vp;

__device__ __forceinline__ void gload_lds16(const bf16* g, bf16* lds_uni) {
    __builtin_amdgcn_global_load_lds((as1_cvp)g, (as3_vp)lds_uni, 16, 0, 0);
}

// ---------------------------------------------------------------------------
// Single-launch fp32 -> bf16 convert of all 5 inputs (segmented grid).
// ---------------------------------------------------------------------------
__global__ __launch_bounds__(256) void cvt_all(
    const float* __restrict__ a0, const float* __restrict__ a1,
    const float* __restrict__ a2, const float* __restrict__ a3,
    const float* __restrict__ a4,
    bf16* __restrict__ d0, bf16* __restrict__ d1, bf16* __restrict__ d2,
    bf16* __restrict__ d3, bf16* __restrict__ d4)
{
    const int b = blockIdx.x;
    const float* src; bf16* dst; int off;
    if (b < 2048)      { src = a0; dst = d0; off = b; }
    else if (b < 4096) { src = a1; dst = d1; off = b - 2048; }
    else if (b < 4608) { src = a2; dst = d2; off = b - 4096; }
    else if (b < 5120) { src = a3; dst = d3; off = b - 4608; }
    else               { src = a4; dst = d4; off = b - 5120; }
    const int i = (off * 256 + threadIdx.x) * 8;
    const float4 x = *(const float4*)(src + i);
    const float4 y = *(const float4*)(src + i + 4);
    bf16 t[8];
    t[0] = __float2bfloat16(x.x); t[1] = __float2bfloat16(x.y);
    t[2] = __float2bfloat16(x.z); t[3] = __float2bfloat16(x.w);
    t[4] = __float2bfloat16(y.x); t[5] = __float2bfloat16(y.y);
    t[6] = __float2bfloat16(y.z); t[7] = __float2bfloat16(y.w);
    *(short8*)(dst + i) = *(const short8*)t;
}

// ---------------------------------------------------------------------------
// GEMM K-loop core: two 32-wide K-slices per barrier pair (BK=64). Stride-32
// fragment reads keep bank-optimal m97 pattern. LDK = global row stride,
// loop extent KB, base pre-offset for split-K.
// ---------------------------------------------------------------------------
#define GEMM_K_LOOP(KB, LDK)                                                    \
    for (int k0 = 0; k0 < (KB); k0 += 64) {                                     \
        gload_lds16(gA + k0,            ldsA0);                                 \
        gload_lds16(gA + K64 + k0,      ldsA1);                                 \
        gload_lds16(gB + k0,            ldsB0);                                 \
        gload_lds16(gB + K64 + k0,      ldsB1);                                 \
        gload_lds16(gA + k0 + 32,       ldsA0 + 4096);                          \
        gload_lds16(gA + K64 + k0 + 32, ldsA1 + 4096);                          \
        gload_lds16(gB + k0 + 32,       ldsB0 + 4096);                          \
        gload_lds16(gB + K64 + k0 + 32, ldsB1 + 4096);                          \
        __syncthreads();                                                        \
        _Pragma("unroll")                                                       \
        for (int hh = 0; hh < 2; ++hh) {                                        \
            short8 af[4], bfr[4];                                               \
            _Pragma("unroll")                                                   \
            for (int i = 0; i < 4; ++i)                                         \
                af[i] = *(const short8*)&As[hh * 4096 + (wm * 64 + i * 16 + l15) * 32 + quad * 8]; \
            _Pragma("unroll")                                                   \
            for (int j = 0; j < 4; ++j)                                         \
                bfr[j] = *(const short8*)&Bs[hh * 4096 + (wn * 64 + j * 16 + l15) * 32 + quad * 8]; \
            _Pragma("unroll")                                                   \
            for (int i = 0; i < 4; ++i)                                         \
                _Pragma("unroll")                                               \
                for (int j = 0; j < 4; ++j)                                     \
                    acc[i][j] = MFMA16(af[i], bfr[j], acc[i][j]);               \
        }                                                                       \
        __syncthreads();                                                        \
    }

// ---------------------------------------------------------------------------
// Fused QKV projection, Q split-K=2. grid (40,16):
//   bx 0..3  : K full-K  (RoPE epilogue -> kb)          [2 work units, first]
//   bx 4..7  : V full-K  (transpose epilogue -> vt)     [2 work units]
//   bx 8..23 : Q K-half0 (raw bf16 partial -> qp0)
//   bx 24..39: Q K-half1 (raw bf16 partial -> qp1)
// RoPE + 1/8 scale for Q applied in merge_q.
// ---------------------------------------------------------------------------
__global__ __launch_bounds__(256) void gemm_qkv(
    const bf16* __restrict__ A, const bf16* __restrict__ Wq,
    const bf16* __restrict__ Wk, const bf16* __restrict__ Wv,
    bf16* __restrict__ qp0, bf16* __restrict__ qp1,
    bf16* __restrict__ kb, bf16* __restrict__ vt)
{
    constexpr int LDK = 2048;
    __shared__ bf16 As[2 * 128 * 32];
    __shared__ bf16 Bs[2 * 128 * 32];

    const int tid  = threadIdx.x;
    const int lane = tid & 63;
    const int w    = tid >> 6;
    const int wm   = w >> 1, wn = w & 1;
    const int quad = lane >> 4, l15 = lane & 15;
    const int bx = blockIdx.x, by = blockIdx.y;

    const bf16* Bp; int bxl, mode, kbeg, kext;
    if (bx < 4)       { Bp = Wk; bxl = bx;      mode = 1; kbeg = 0;    kext = 2048; }
    else if (bx < 8)  { Bp = Wv; bxl = bx - 4;  mode = 2; kbeg = 0;    kext = 2048; }
    else if (bx < 24) { Bp = Wq; bxl = bx - 8;  mode = 0; kbeg = 0;    kext = 1024; }
    else              { Bp = Wq; bxl = bx - 24; mode = 3; kbeg = 1024; kext = 1024; }

    floatx4 acc[4][4];
#pragma unroll
    for (int i = 0; i < 4; ++i)
#pragma unroll
        for (int j = 0; j < 4; ++j) {
            floatx4 z = {0.f, 0.f, 0.f, 0.f};
            acc[i][j] = z;
        }

    const int srow = tid >> 2;
    const int sch  = (tid & 3) * 8;
    const bf16* gA = A  + (size_t)(by * 128 + srow) * LDK + kbeg + sch;
    const bf16* gB = Bp + (size_t)(bxl * 128 + srow) * LDK + kbeg + sch;
    const size_t K64 = (size_t)64 * LDK;
    bf16* ldsA0 = As + w * 512;
    bf16* ldsA1 = As + 2048 + w * 512;
    bf16* ldsB0 = Bs + w * 512;
    bf16* ldsB1 = Bs + 2048 + w * 512;

    GEMM_K_LOOP(kext, LDK)

    // epilogue. C/D layout: col = lane&15, row = quad*4 + reg  [m89/m91]
    if (mode == 2) {
        // V: transpose-store vt[d][s]
#pragma unroll
        for (int i = 0; i < 4; ++i)
#pragma unroll
            for (int j = 0; j < 4; ++j) {
                const int col = bxl * 128 + wn * 64 + j * 16 + l15;
                const int rowb = by * 128 + wm * 64 + i * 16 + quad * 4;
                bf16 t[4];
#pragma unroll
                for (int r = 0; r < 4; ++r) t[r] = __float2bfloat16(acc[i][j][r]);
                *(short4v*)&vt[(size_t)col * 2048 + rowb] = *(const short4v*)t;
            }
    } else if (mode == 1) {
        // K: RoPE epilogue
        const float LOG2_1E4 = 13.28771237954945f;
        const float ifr0 = exp2f(-((float)l15) * (LOG2_1E4 / 32.f));
        const float ifr1 = exp2f(-((float)(16 + l15)) * (LOG2_1E4 / 32.f));
#pragma unroll
        for (int i = 0; i < 4; ++i) {
#pragma unroll
            for (int r = 0; r < 4; ++r) {
                const int row = by * 128 + wm * 64 + i * 16 + quad * 4 + r;
                float s0, c0, s1, c1;
                sincosf((float)row * ifr0, &s0, &c0);
                sincosf((float)row * ifr1, &s1, &c1);
#pragma unroll
                for (int j = 0; j < 4; ++j) {
                    const float x  = acc[i][j][r];
                    const float xp = acc[i][j ^ 2][r];
                    const float cs = (j & 1) ? c1 : c0;
                    const float sn = (j & 1) ? s1 : s0;
                    const float oo = x * cs + ((j < 2) ? -xp : xp) * sn;
                    const int col = bxl * 128 + wn * 64 + j * 16 + l15;
                    kb[(size_t)row * 512 + col] = __float2bfloat16(oo);
                }
            }
        }
    } else {
        // Q partial: raw bf16 store
        bf16* C = (mode == 0) ? qp0 : qp1;
#pragma unroll
        for (int i = 0; i < 4; ++i)
#pragma unroll
            for (int j = 0; j < 4; ++j)
#pragma unroll
                for (int r = 0; r < 4; ++r) {
                    const int row = by * 128 + wm * 64 + i * 16 + quad * 4 + r;
                    const int col = bxl * 128 + wn * 64 + j * 16 + l15;
                    C[(size_t)row * 2048 + col] = __float2bfloat16(acc[i][j][r]);
                }
    }
}

// ---------------------------------------------------------------------------
// merge_q: qb = rope(qp0 + qp1) * 0.125. Elementwise (partner d +/- 32 in
// same row). Block = 2 rows; 128 threads/row; thread: head = (t&127)>>2,
// dd0 = (t&3)*8, produces d=dd0..+7 and d+32..+39.  grid 1024.
// ---------------------------------------------------------------------------
__global__ __launch_bounds__(256) void merge_q(
    const bf16* __restrict__ qp0, const bf16* __restrict__ qp1,
    bf16* __restrict__ qb)
{
    const int t = threadIdx.x;
    const int row = blockIdx.x * 2 + (t >> 7);
    const int i7 = t & 127;
    const int head = i7 >> 2;
    const int dd0 = (i7 & 3) * 8;
    const size_t base = (size_t)row * 2048 + head * 64;

    short8 a0 = *(const short8*)(qp0 + base + dd0);
    short8 a1 = *(const short8*)(qp1 + base + dd0);
    short8 b0 = *(const short8*)(qp0 + base + 32 + dd0);
    short8 b1 = *(const short8*)(qp1 + base + 32 + dd0);
    const bf16* pa0 = (const bf16*)&a0; const bf16* pa1 = (const bf16*)&a1;
    const bf16* pb0 = (const bf16*)&b0; const bf16* pb1 = (const bf16*)&b1;

    const float LOG2_1E4 = 13.28771237954945f;
    bf16 o0[8], o1[8];
#pragma unroll
    for (int j = 0; j < 8; ++j) {
        const float x = __bfloat162float(pa0[j]) + __bfloat162float(pa1[j]);
        const float y = __bfloat162float(pb0[j]) + __bfloat162float(pb1[j]);
        const float ifr = exp2f(-((float)(dd0 + j)) * (LOG2_1E4 / 32.f));
        float sn, cs;
        sincosf((float)row * ifr, &sn, &cs);
        o0[j] = __float2bfloat16((x * cs - y * sn) * 0.125f);
        o1[j] = __float2bfloat16((y * cs + x * sn) * 0.125f);
    }
    *(short8*)(qb + base + dd0)      = *(const short8*)o0;
    *(short8*)(qb + base + 32 + dd0) = *(const short8*)o1;
}

// ---------------------------------------------------------------------------
// O-projection, split-K=2: fp32 partials. grid (32,16): bx<16 -> half0.
// ---------------------------------------------------------------------------
__global__ __launch_bounds__(256) void gemm_out(
    const bf16* __restrict__ A, const bf16* __restrict__ B,
    float* __restrict__ op0, float* __restrict__ op1)
{
    constexpr int LDK = 2048;
    __shared__ bf16 As[2 * 128 * 32];
    __shared__ bf16 Bs[2 * 128 * 32];

    const int tid  = threadIdx.x;
    const int lane = tid & 63;
    const int w    = tid >> 6;
    const int wm   = w >> 1, wn = w & 1;
    const int quad = lane >> 4, l15 = lane & 15;
    const int bxr = blockIdx.x, by = blockIdx.y;
    const int kh  = bxr >> 4;
    const int bx  = bxr & 15;
    const int kbeg = kh * 1024;
    float* C = kh ? op1 : op0;

    floatx4 acc[4][4];
#pragma unroll
    for (int i = 0; i < 4; ++i)
#pragma unroll
        for (int j = 0; j < 4; ++j) {
            floatx4 z = {0.f, 0.f, 0.f, 0.f};
            acc[i][j] = z;
        }

    const int srow = tid >> 2;
    const int sch  = (tid & 3) * 8;
    const bf16* gA = A + (size_t)(by * 128 + srow) * LDK + kbeg + sch;
    const bf16* gB = B + (size_t)(bx * 128 + srow) * LDK + kbeg + sch;
    const size_t K64 = (size_t)64 * LDK;
    bf16* ldsA0 = As + w * 512;
    bf16* ldsA1 = As + 2048 + w * 512;
    bf16* ldsB0 = Bs + w * 512;
    bf16* ldsB1 = Bs + 2048 + w * 512;

    GEMM_K_LOOP(1024, LDK)

#pragma unroll
    for (int i = 0; i < 4; ++i)
#pragma unroll
        for (int j = 0; j < 4; ++j)
#pragma unroll
            for (int r = 0; r < 4; ++r) {
                const int row = by * 128 + wm * 64 + i * 16 + quad * 4 + r;
                const int col = bx * 128 + wn * 64 + j * 16 + l15;
                C[(size_t)row * 2048 + col] = acc[i][j][r];
            }
}

// ---------------------------------------------------------------------------
// merge_out: out = op0 + op1 (fp32 elementwise). grid 2048, 8 elems/thread.
// ---------------------------------------------------------------------------
__global__ __launch_bounds__(256) void merge_out(
    const float* __restrict__ op0, const float* __restrict__ op1,
    float* __restrict__ out)
{
    const int i = (blockIdx.x * 256 + threadIdx.x) * 8;
    const float4 a0 = *(const float4*)(op0 + i);
    const float4 a1 = *(const float4*)(op0 + i + 4);
    const float4 b0 = *(const float4*)(op1 + i);
    const float4 b1 = *(const float4*)(op1 + i + 4);
    float4 r0 = {a0.x + b0.x, a0.y + b0.y, a0.z + b0.z, a0.w + b0.w};
    float4 r1 = {a1.x + b1.x, a1.y + b1.y, a1.z + b1.z, a1.w + b1.w};
    *(float4*)(out + i)     = r0;
    *(float4*)(out + i + 4) = r1;
}

// ---------------------------------------------------------------------------
// Causal GQA flash attention v4 (round-6 verified, 60.2us): 16 q-rows/wave,
// uniform causal pairing (tile t + tile 31-t = 33 iters/block), grid (16,32)
// = 512 blocks = 2/CU. Stride-72 LDS K/V dbuf, reg prefetch, 1 barrier/iter,
// wave-private stride-68 P, no max-subtract, ones-MFMA row-sum.
// ---------------------------------------------------------------------------
__global__ __launch_bounds__(256) void fattn4(
    const bf16* __restrict__ q, const bf16* __restrict__ k,
    const bf16* __restrict__ vt, bf16* __restrict__ o)
{
    __shared__ bf16 Ks[2][64 * 72];
    __shared__ bf16 Vs[2][64 * 72];
    __shared__ bf16 Ps[4][16 * 68];

    const int tpair = blockIdx.x;
    const int h = blockIdx.y;
    const int kvh = h >> 2;
    const int tid = threadIdx.x, lane = tid & 63, w = tid >> 6;
    const int quad = lane >> 4, l15 = lane & 15;
    bf16* P = Ps[w];

    short ob[8];
#pragma unroll
    for (int e = 0; e < 8; ++e) ob[e] = (short)0x3F80;  // bf16 1.0
    const short8 ones = *(const short8*)ob;

    const int srow = tid >> 3;
    const int ch8  = (tid & 7) * 8;
    const bf16* kg = k  + (size_t)kvh * 64 + ch8;
    const bf16* vg = vt + (size_t)(kvh * 64 + srow) * 2048 + ch8;

#pragma unroll 1
    for (int ph = 0; ph < 2; ++ph) {
        const int a = ph ? (31 - tpair) : tpair;
        const int qrow0 = a * 64 + w * 16;

        short8 qf[2];
#pragma unroll
        for (int ks = 0; ks < 2; ++ks)
            qf[ks] = *(const short8*)&q[(size_t)(qrow0 + l15) * 2048 + h * 64 + ks * 32 + quad * 8];

        floatx4 o_acc[4], l_acc;
#pragma unroll
        for (int n4 = 0; n4 < 4; ++n4) {
            floatx4 z = {0.f, 0.f, 0.f, 0.f};
            o_acc[n4] = z;
        }
        { floatx4 z = {0.f, 0.f, 0.f, 0.f}; l_acc = z; }

        {
            short8 k0 = *(const short8*)(kg + (size_t)srow * 512);
            short8 k1 = *(const short8*)(kg + (size_t)(srow + 32) * 512);
            short8 v0 = *(const short8*)(vg);
            short8 v1 = *(const short8*)(vg + (size_t)32 * 2048);
            *(short8*)&Ks[0][srow * 72 + ch8]        = k0;
            *(short8*)&Ks[0][(srow + 32) * 72 + ch8] = k1;
            *(short8*)&Vs[0][srow * 72 + ch8]        = v0;
            *(short8*)&Vs[0][(srow + 32) * 72 + ch8] = v1;
        }
        __syncthreads();

        for (int kt = 0; kt <= a; ++kt) {
            const int buf = kt & 1;

            short8 nk0, nk1, nv0, nv1;
            if (kt < a) {
                const size_t kr = (size_t)((kt + 1) * 64) * 512;
                nk0 = *(const short8*)(kg + kr + (size_t)srow * 512);
                nk1 = *(const short8*)(kg + kr + (size_t)(srow + 32) * 512);
                nv0 = *(const short8*)(vg + (kt + 1) * 64);
                nv1 = *(const short8*)(vg + (size_t)32 * 2048 + (kt + 1) * 64);
            }

            floatx4 s_acc[4];
#pragma unroll
            for (int n = 0; n < 4; ++n) {
                floatx4 z = {0.f, 0.f, 0.f, 0.f};
                s_acc[n] = z;
            }
#pragma unroll
            for (int n = 0; n < 4; ++n)
#pragma unroll
                for (int ks = 0; ks < 2; ++ks) {
                    const short8 kf = *(const short8*)&Ks[buf][(n * 16 + l15) * 72 + ks * 32 + quad * 8];
                    s_acc[n] = MFMA16(qf[ks], kf, s_acc[n]);
                }

            if (kt < a) {
#pragma unroll
                for (int n = 0; n < 4; ++n)
#pragma unroll
                    for (int r = 0; r < 4; ++r)
                        P[(quad * 4 + r) * 68 + n * 16 + l15] = __float2bfloat16(__expf(s_acc[n][r]));
            } else {
#pragma unroll
                for (int n = 0; n < 4; ++n)
#pragma unroll
                    for (int r = 0; r < 4; ++r) {
                        const bool okc = (n * 16 + l15) <= (w * 16 + quad * 4 + r);
                        const float p = okc ? __expf(s_acc[n][r]) : 0.f;
                        P[(quad * 4 + r) * 68 + n * 16 + l15] = __float2bfloat16(p);
                    }
            }

#pragma unroll
            for (int ks2 = 0; ks2 < 2; ++ks2) {
                const short8 pf = *(const short8*)&P[l15 * 68 + ks2 * 32 + quad * 8];
                l_acc = MFMA16(pf, ones, l_acc);
#pragma unroll
                for (int n4 = 0; n4 < 4; ++n4) {
                    const short8 vf = *(const short8*)&Vs[buf][(n4 * 16 + l15) * 72 + ks2 * 32 + quad * 8];
                    o_acc[n4] = MFMA16(pf, vf, o_acc[n4]);
                }
            }

            if (kt < a) {
                *(short8*)&Ks[buf ^ 1][srow * 72 + ch8]        = nk0;
                *(short8*)&Ks[buf ^ 1][(srow + 32) * 72 + ch8] = nk1;
                *(short8*)&Vs[buf ^ 1][srow * 72 + ch8]        = nv0;
                *(short8*)&Vs[buf ^ 1][(srow + 32) * 72 + ch8] = nv1;
            }
            __syncthreads();
        }

#pragma unroll
        for (int n4 = 0; n4 < 4; ++n4)
#pragma unroll
            for (int r = 0; r < 4; ++r) {
                const float val = o_acc[n4][r] / l_acc[r];
                const int row = qrow0 + quad * 4 + r;
                const int col = h * 64 + n4 * 16 + l15;
                o[(size_t)row * 2048 + col] = __float2bfloat16(val);
            }
    }
}

// ---------------------------------------------------------------------------
extern "C" void kernel_launch(void* const* d_in, const int* in_sizes, int n_in,
                              void* d_out, int out_size, void* d_ws, size_t ws_size,
                              hipStream_t stream)
{
    const float* hs = (const float*)d_in[0];
    const float* Wq = (const float*)d_in[1];
    const float* Wk = (const float*)d_in[2];
    const float* Wv = (const float*)d_in[3];
    const float* Wo = (const float*)d_in[4];
    float* out = (float*)d_out;

    // ws layout (bf16 slots). fp32 O-partials alias slots [0, 16777216)
    // (hsb..vtb), all dead by the time gemm_out runs.
    bf16* ws  = (bf16*)d_ws;
    bf16* hsb = ws;                  // +0         4,194,304
    bf16* Wqb = ws + 4194304;        //            4,194,304
    bf16* Wkb = ws + 8388608;        //            1,048,576
    bf16* Wvb = ws + 9437184;        //            1,048,576
    bf16* qb  = ws + 10485760;       //            4,194,304  (RoPE'd, 1/8-scaled)
    bf16* kb  = ws + 14680064;       //            1,048,576  (RoPE'd)
    bf16* vtb = ws + 15728640;       //            1,048,576  (V^T [512][2048])
    bf16* ab  = ws + 16777216;       //            4,194,304  (attention out)
    bf16* Wob = ws + 20971520;       //            4,194,304
    bf16* qp0 = ws + 25165824;       //            4,194,304  (Q K-half0 partial)
    bf16* qp1 = ws + 29360128;       //            4,194,304  (Q K-half1 partial)
    float* op0 = (float*)d_ws;                 // 4,194,304 fp32
    float* op1 = (float*)d_ws + 4194304;       // 4,194,304 fp32 (ends at slot 16777216)

    dim3 blk(256);
    cvt_all<<<7168, blk, 0, stream>>>(hs, Wq, Wk, Wv, Wo, hsb, Wqb, Wkb, Wvb, Wob);
    gemm_qkv<<<dim3(40, 16), blk, 0, stream>>>(hsb, Wqb, Wkb, Wvb, qp0, qp1, kb, vtb);
    merge_q<<<1024, blk, 0, stream>>>(qp0, qp1, qb);
    fattn4<<<dim3(16, 32), blk, 0, stream>>>(qb, kb, vtb, ab);
    gemm_out<<<dim3(32, 16), blk, 0, stream>>>(ab, Wob, op0, op1);
    merge_out<<<2048, blk, 0, stream>>>(op0, op1, out);
}

// Round 9
// 223.041 us; speedup vs baseline: 1.1392x; 1.1392x over previous
//
#include <hip/hip_runtime.h>
#include <hip/hip_bf16.h>
#include <math.h>

typedef __hip_bfloat16 bf16;
typedef __attribute__((ext_vector_type(8))) short short8;
typedef __attribute__((ext_vector_type(4))) short short4v;
typedef __attribute__((ext_vector_type(4))) float floatx4;

#define MFMA16(a, b, c) __builtin_amdgcn_mfma_f32_16x16x32_bf16((a), (b), (c), 0, 0, 0)

typedef const __attribute__((address_space(1))) void* as1_cvp;
typedef __attribute__((address_space(3))) void* as3_vp;

__device__ __forceinline__ void gload_lds16(const bf16* g, bf16* lds_uni) {
    __builtin_amdgcn_global_load_lds((as1_cvp)g, (as3_vp)lds_uni, 16, 0, 0);
}

// ---------------------------------------------------------------------------
// Single-launch fp32 -> bf16 convert of all 5 inputs (segmented grid).
// ---------------------------------------------------------------------------
__global__ __launch_bounds__(256) void cvt_all(
    const float* __restrict__ a0, const float* __restrict__ a1,
    const float* __restrict__ a2, const float* __restrict__ a3,
    const float* __restrict__ a4,
    bf16* __restrict__ d0, bf16* __restrict__ d1, bf16* __restrict__ d2,
    bf16* __restrict__ d3, bf16* __restrict__ d4)
{
    const int b = blockIdx.x;
    const float* src; bf16* dst; int off;
    if (b < 2048)      { src = a0; dst = d0; off = b; }
    else if (b < 4096) { src = a1; dst = d1; off = b - 2048; }
    else if (b < 4608) { src = a2; dst = d2; off = b - 4096; }
    else if (b < 5120) { src = a3; dst = d3; off = b - 4608; }
    else               { src = a4; dst = d4; off = b - 5120; }
    const int i = (off * 256 + threadIdx.x) * 8;
    const float4 x = *(const float4*)(src + i);
    const float4 y = *(const float4*)(src + i + 4);
    bf16 t[8];
    t[0] = __float2bfloat16(x.x); t[1] = __float2bfloat16(x.y);
    t[2] = __float2bfloat16(x.z); t[3] = __float2bfloat16(x.w);
    t[4] = __float2bfloat16(y.x); t[5] = __float2bfloat16(y.y);
    t[6] = __float2bfloat16(y.z); t[7] = __float2bfloat16(y.w);
    *(short8*)(dst + i) = *(const short8*)t;
}

// ---------------------------------------------------------------------------
// 128x64-tile GEMM K-loop (BK=64 as two 32-slices per barrier pair).
// 4 waves, each 32 rows x 64 cols (acc[2][4]). 6 async stages + 12 b128
// reads feed 16 MFMAs/wave per pair. More blocks (uniform work) = the
// inter-block overlap the 128x128 config lacked at N=2048 scale.
// ---------------------------------------------------------------------------
#define GEMM_K_LOOP_12864(KB)                                                   \
    for (int k0 = 0; k0 < (KB); k0 += 64) {                                     \
        gload_lds16(gA + k0,            ldsA);                                  \
        gload_lds16(gA + A64 + k0,      ldsA + 2048);                           \
        gload_lds16(gB + k0,            ldsB);                                  \
        gload_lds16(gA + k0 + 32,       ldsA + 4096);                           \
        gload_lds16(gA + A64 + k0 + 32, ldsA + 6144);                           \
        gload_lds16(gB + k0 + 32,       ldsB + 2048);                           \
        __syncthreads();                                                        \
        _Pragma("unroll")                                                       \
        for (int hh = 0; hh < 2; ++hh) {                                        \
            short8 af[2], bfr[4];                                               \
            _Pragma("unroll")                                                   \
            for (int i = 0; i < 2; ++i)                                         \
                af[i] = *(const short8*)&As[hh * 4096 + (w * 32 + i * 16 + l15) * 32 + quad * 8]; \
            _Pragma("unroll")                                                   \
            for (int j = 0; j < 4; ++j)                                         \
                bfr[j] = *(const short8*)&Bs[hh * 2048 + (j * 16 + l15) * 32 + quad * 8]; \
            _Pragma("unroll")                                                   \
            for (int i = 0; i < 2; ++i)                                         \
                _Pragma("unroll")                                               \
                for (int j = 0; j < 4; ++j)                                     \
                    acc[i][j] = MFMA16(af[i], bfr[j], acc[i][j]);               \
        }                                                                       \
        __syncthreads();                                                        \
    }

// ---------------------------------------------------------------------------
// Fused QKV projection, 128x64 tiles. grid (48,16):
//   bx  0..31: Q (RoPE + 1/8 scale -> qb)
//   bx 32..39: K (RoPE -> kb)
//   bx 40..47: V (transpose-store -> vt[512][2048])
// All blocks uniform full-K work (round-8 imbalance removed).
// ---------------------------------------------------------------------------
__global__ __launch_bounds__(256) void gemm_qkv(
    const bf16* __restrict__ A, const bf16* __restrict__ Wq,
    const bf16* __restrict__ Wk, const bf16* __restrict__ Wv,
    bf16* __restrict__ qb, bf16* __restrict__ kb, bf16* __restrict__ vt)
{
    constexpr int LDK = 2048;
    __shared__ bf16 As[2 * 128 * 32];   // 16 KB
    __shared__ bf16 Bs[2 * 64 * 32];    //  8 KB

    const int tid  = threadIdx.x;
    const int lane = tid & 63;
    const int w    = tid >> 6;
    const int quad = lane >> 4, l15 = lane & 15;
    const int bx = blockIdx.x, by = blockIdx.y;

    const bf16* Bp; int bxl, mode;
    if (bx < 32)      { Bp = Wq; bxl = bx;      mode = 0; }
    else if (bx < 40) { Bp = Wk; bxl = bx - 32; mode = 1; }
    else              { Bp = Wv; bxl = bx - 40; mode = 2; }

    floatx4 acc[2][4];
#pragma unroll
    for (int i = 0; i < 2; ++i)
#pragma unroll
        for (int j = 0; j < 4; ++j) {
            floatx4 z = {0.f, 0.f, 0.f, 0.f};
            acc[i][j] = z;
        }

    const int srow = tid >> 2;          // 0..63
    const int sch  = (tid & 3) * 8;
    const bf16* gA = A  + (size_t)(by * 128 + srow) * LDK + sch;
    const bf16* gB = Bp + (size_t)(bxl * 64 + srow) * LDK + sch;
    const size_t A64 = (size_t)64 * LDK;
    bf16* ldsA = As + w * 512;
    bf16* ldsB = Bs + w * 512;

    GEMM_K_LOOP_12864(LDK)

    // epilogue. C/D layout: col = lane&15, row = quad*4 + reg  [m89/m91]
    if (mode == 2) {
        // V: transpose-store vt[d][s], 4 consecutive s packed -> b64
#pragma unroll
        for (int i = 0; i < 2; ++i)
#pragma unroll
            for (int j = 0; j < 4; ++j) {
                const int col = bxl * 64 + j * 16 + l15;                  // d
                const int rowb = by * 128 + w * 32 + i * 16 + quad * 4;   // s base
                bf16 t[4];
#pragma unroll
                for (int r = 0; r < 4; ++r) t[r] = __float2bfloat16(acc[i][j][r]);
                *(short4v*)&vt[(size_t)col * 2048 + rowb] = *(const short4v*)t;
            }
    } else {
        // Q/K: RoPE (head dim 64; tile is head-aligned, d = j*16+l15,
        // partner j^2 in-wave). Q also pre-scaled by 1/8.
        bf16* C = (mode == 0) ? qb : kb;
        const int Nn = (mode == 0) ? 2048 : 512;
        const float scale = (mode == 0) ? 0.125f : 1.0f;
        const float LOG2_1E4 = 13.28771237954945f;
        const float ifr0 = exp2f(-((float)l15) * (LOG2_1E4 / 32.f));
        const float ifr1 = exp2f(-((float)(16 + l15)) * (LOG2_1E4 / 32.f));
#pragma unroll
        for (int i = 0; i < 2; ++i) {
#pragma unroll
            for (int r = 0; r < 4; ++r) {
                const int row = by * 128 + w * 32 + i * 16 + quad * 4 + r;
                float s0, c0, s1, c1;
                sincosf((float)row * ifr0, &s0, &c0);
                sincosf((float)row * ifr1, &s1, &c1);
#pragma unroll
                for (int j = 0; j < 4; ++j) {
                    const float x  = acc[i][j][r];
                    const float xp = acc[i][j ^ 2][r];
                    const float cs = (j & 1) ? c1 : c0;
                    const float sn = (j & 1) ? s1 : s0;
                    const float oo = (x * cs + ((j < 2) ? -xp : xp) * sn) * scale;
                    const int col = bxl * 64 + j * 16 + l15;
                    C[(size_t)row * Nn + col] = __float2bfloat16(oo);
                }
            }
        }
    }
}

// ---------------------------------------------------------------------------
// O-projection, 128x64 tiles: grid (32,16) = 512 blocks. fp32 store.
// ---------------------------------------------------------------------------
__global__ __launch_bounds__(256) void gemm_out(
    const bf16* __restrict__ A, const bf16* __restrict__ B, float* __restrict__ C)
{
    constexpr int LDK = 2048;
    __shared__ bf16 As[2 * 128 * 32];
    __shared__ bf16 Bs[2 * 64 * 32];

    const int tid  = threadIdx.x;
    const int lane = tid & 63;
    const int w    = tid >> 6;
    const int quad = lane >> 4, l15 = lane & 15;
    const int bx = blockIdx.x, by = blockIdx.y;

    floatx4 acc[2][4];
#pragma unroll
    for (int i = 0; i < 2; ++i)
#pragma unroll
        for (int j = 0; j < 4; ++j) {
            floatx4 z = {0.f, 0.f, 0.f, 0.f};
            acc[i][j] = z;
        }

    const int srow = tid >> 2;
    const int sch  = (tid & 3) * 8;
    const bf16* gA = A + (size_t)(by * 128 + srow) * LDK + sch;
    const bf16* gB = B + (size_t)(bx * 64 + srow) * LDK + sch;
    const size_t A64 = (size_t)64 * LDK;
    bf16* ldsA = As + w * 512;
    bf16* ldsB = Bs + w * 512;

    GEMM_K_LOOP_12864(LDK)

#pragma unroll
    for (int i = 0; i < 2; ++i)
#pragma unroll
        for (int j = 0; j < 4; ++j)
#pragma unroll
            for (int r = 0; r < 4; ++r) {
                const int row = by * 128 + w * 32 + i * 16 + quad * 4 + r;
                const int col = bx * 64 + j * 16 + l15;
                C[(size_t)row * 2048 + col] = acc[i][j][r];
            }
}

// ---------------------------------------------------------------------------
// Causal GQA flash attention v4b: round-6 fattn4 (60.2us measured) with the
// S^T trick: compute S^T = MFMA(K-frag, Q-frag) so each lane holds 4
// CONSECUTIVE skeys (row=quad*4+r) for one qrow (col=l15) -> P written as
// 4x b64 instead of 16x b16 (fattn4 was LDS-pipe-bound; -12 DS ops of ~38
// per wave-iter). Reads (kf/vf/pf b128), PV, ones-MFMA row-sum, pairing
// (tile t + 31-t = uniform 33 iters), stride-72 dbuf staging: unchanged.
// ---------------------------------------------------------------------------
__global__ __launch_bounds__(256) void fattn4b(
    const bf16* __restrict__ q, const bf16* __restrict__ k,
    const bf16* __restrict__ vt, bf16* __restrict__ o)
{
    __shared__ bf16 Ks[2][64 * 72];
    __shared__ bf16 Vs[2][64 * 72];
    __shared__ bf16 Ps[4][16 * 68];

    const int tpair = blockIdx.x;
    const int h = blockIdx.y;
    const int kvh = h >> 2;             // GQA groups = 4
    const int tid = threadIdx.x, lane = tid & 63, w = tid >> 6;
    const int quad = lane >> 4, l15 = lane & 15;
    bf16* P = Ps[w];

    short ob[8];
#pragma unroll
    for (int e = 0; e < 8; ++e) ob[e] = (short)0x3F80;  // bf16 1.0
    const short8 ones = *(const short8*)ob;

    const int srow = tid >> 3;
    const int ch8  = (tid & 7) * 8;
    const bf16* kg = k  + (size_t)kvh * 64 + ch8;
    const bf16* vg = vt + (size_t)(kvh * 64 + srow) * 2048 + ch8;

#pragma unroll 1
    for (int ph = 0; ph < 2; ++ph) {
        const int a = ph ? (31 - tpair) : tpair;
        const int qrow0 = a * 64 + w * 16;

        short8 qf[2];
#pragma unroll
        for (int ks = 0; ks < 2; ++ks)
            qf[ks] = *(const short8*)&q[(size_t)(qrow0 + l15) * 2048 + h * 64 + ks * 32 + quad * 8];

        floatx4 o_acc[4], l_acc;
#pragma unroll
        for (int n4 = 0; n4 < 4; ++n4) {
            floatx4 z = {0.f, 0.f, 0.f, 0.f};
            o_acc[n4] = z;
        }
        { floatx4 z = {0.f, 0.f, 0.f, 0.f}; l_acc = z; }

        {
            short8 k0 = *(const short8*)(kg + (size_t)srow * 512);
            short8 k1 = *(const short8*)(kg + (size_t)(srow + 32) * 512);
            short8 v0 = *(const short8*)(vg);
            short8 v1 = *(const short8*)(vg + (size_t)32 * 2048);
            *(short8*)&Ks[0][srow * 72 + ch8]        = k0;
            *(short8*)&Ks[0][(srow + 32) * 72 + ch8] = k1;
            *(short8*)&Vs[0][srow * 72 + ch8]        = v0;
            *(short8*)&Vs[0][(srow + 32) * 72 + ch8] = v1;
        }
        __syncthreads();

        for (int kt = 0; kt <= a; ++kt) {
            const int buf = kt & 1;

            short8 nk0, nk1, nv0, nv1;
            if (kt < a) {
                const size_t kr = (size_t)((kt + 1) * 64) * 512;
                nk0 = *(const short8*)(kg + kr + (size_t)srow * 512);
                nk1 = *(const short8*)(kg + kr + (size_t)(srow + 32) * 512);
                nv0 = *(const short8*)(vg + (kt + 1) * 64);
                nv1 = *(const short8*)(vg + (size_t)32 * 2048 + (kt + 1) * 64);
            }

            // S^T = K Q^T: A=kf (m=skey), B=qf (n=qrow).
            // C: col=l15 -> qrow, row=quad*4+r -> skey = n*16+quad*4+r.
            floatx4 s_acc[4];
#pragma unroll
            for (int n = 0; n < 4; ++n) {
                floatx4 z = {0.f, 0.f, 0.f, 0.f};
                s_acc[n] = z;
            }
#pragma unroll
            for (int n = 0; n < 4; ++n)
#pragma unroll
                for (int ks = 0; ks < 2; ++ks) {
                    const short8 kf = *(const short8*)&Ks[buf][(n * 16 + l15) * 72 + ks * 32 + quad * 8];
                    s_acc[n] = MFMA16(kf, qf[ks], s_acc[n]);
                }

            // exp -> P[qrow][skey], 4 consecutive skeys per lane -> b64 write
            if (kt < a) {
#pragma unroll
                for (int n = 0; n < 4; ++n) {
                    bf16 t4[4];
#pragma unroll
                    for (int r = 0; r < 4; ++r)
                        t4[r] = __float2bfloat16(__expf(s_acc[n][r]));
                    *(short4v*)&P[l15 * 68 + n * 16 + quad * 4] = *(const short4v*)t4;
                }
            } else {
                // diagonal: allow skey <= qrow (within 64-row block)
#pragma unroll
                for (int n = 0; n < 4; ++n) {
                    bf16 t4[4];
#pragma unroll
                    for (int r = 0; r < 4; ++r) {
                        const bool okc = (n * 16 + quad * 4 + r) <= (w * 16 + l15);
                        t4[r] = __float2bfloat16(okc ? __expf(s_acc[n][r]) : 0.f);
                    }
                    *(short4v*)&P[l15 * 68 + n * 16 + quad * 4] = *(const short4v*)t4;
                }
            }

#pragma unroll
            for (int ks2 = 0; ks2 < 2; ++ks2) {
                const short8 pf = *(const short8*)&P[l15 * 68 + ks2 * 32 + quad * 8];
                l_acc = MFMA16(pf, ones, l_acc);
#pragma unroll
                for (int n4 = 0; n4 < 4; ++n4) {
                    const short8 vf = *(const short8*)&Vs[buf][(n4 * 16 + l15) * 72 + ks2 * 32 + quad * 8];
                    o_acc[n4] = MFMA16(pf, vf, o_acc[n4]);
                }
            }

            if (kt < a) {
                *(short8*)&Ks[buf ^ 1][srow * 72 + ch8]        = nk0;
                *(short8*)&Ks[buf ^ 1][(srow + 32) * 72 + ch8] = nk1;
                *(short8*)&Vs[buf ^ 1][srow * 72 + ch8]        = nv0;
                *(short8*)&Vs[buf ^ 1][(srow + 32) * 72 + ch8] = nv1;
            }
            __syncthreads();
        }

#pragma unroll
        for (int n4 = 0; n4 < 4; ++n4)
#pragma unroll
            for (int r = 0; r < 4; ++r) {
                const float val = o_acc[n4][r] / l_acc[r];
                const int row = qrow0 + quad * 4 + r;
                const int col = h * 64 + n4 * 16 + l15;
                o[(size_t)row * 2048 + col] = __float2bfloat16(val);
            }
    }
}

// ---------------------------------------------------------------------------
extern "C" void kernel_launch(void* const* d_in, const int* in_sizes, int n_in,
                              void* d_out, int out_size, void* d_ws, size_t ws_size,
                              hipStream_t stream)
{
    const float* hs = (const float*)d_in[0];
    const float* Wq = (const float*)d_in[1];
    const float* Wk = (const float*)d_in[2];
    const float* Wv = (const float*)d_in[3];
    const float* Wo = (const float*)d_in[4];
    float* out = (float*)d_out;

    bf16* ws  = (bf16*)d_ws;
    bf16* hsb = ws;                  // 4,194,304
    bf16* Wqb = ws + 4194304;        // 4,194,304
    bf16* Wkb = ws + 8388608;        // 1,048,576
    bf16* Wvb = ws + 9437184;        // 1,048,576
    bf16* Wob = ws + 10485760;       // 4,194,304
    bf16* qb  = ws + 14680064;       // 4,194,304  (RoPE'd, 1/8-scaled)
    bf16* kb  = ws + 18874368;       // 1,048,576  (RoPE'd)
    bf16* vtb = ws + 19922944;       // 1,048,576  (V^T [512][2048])
    bf16* ab  = ws + 20971520;       // 4,194,304  (attention out)

    dim3 blk(256);
    cvt_all<<<7168, blk, 0, stream>>>(hs, Wq, Wk, Wv, Wo, hsb, Wqb, Wkb, Wvb, Wob);
    gemm_qkv<<<dim3(48, 16), blk, 0, stream>>>(hsb, Wqb, Wkb, Wvb, qb, kb, vtb);
    fattn4b<<<dim3(16, 32), blk, 0, stream>>>(qb, kb, vtb, ab);
    gemm_out<<<dim3(32, 16), blk, 0, stream>>>(ab, Wob, out);
}